// Round 1
// baseline (53.815 us; speedup 1.0000x reference)
//
#include <hip/hip_runtime.h>

// Problem constants (fixed by the reference):
//   B=8, N=256, IN_F=64, OUT_F=64, IN_E=32, OUT_E=64
#define BB    8
#define NN    256
#define INF   64
#define OUTF  64
#define INE   32
#define OUTE  64

using f4 = __attribute__((ext_vector_type(4))) float;

// Scratch for the node projections (1 MB total) — device globals so we do not
// depend on ws_size. Fully overwritten by node_proj every call (deterministic).
__device__ float g_node_x[BB * NN * OUTF];   // emb_node@W_node + b_node (pre-relu)
__device__ float g_relu_sx[BB * NN * OUTF];  // relu(emb_node@W_nodes + b_nodes)

// ---------------------------------------------------------------------------
// Kernel 1: node projections. 512 blocks x 256 threads, 4 rows per block.
// Tiny (67 MFLOP, ~1.5 MB traffic) — a few microseconds.
// ---------------------------------------------------------------------------
__global__ __launch_bounds__(256) void node_proj(
    const float* __restrict__ emb_node,  // [B*N, 64]
    const float* __restrict__ W1, const float* __restrict__ b1,
    const float* __restrict__ W2, const float* __restrict__ b2)
{
    __shared__ float sW1[64][64];
    __shared__ float sW2[64][64];
    __shared__ float sE[4][64];

    const int tid = threadIdx.x;

    // Stage both 64x64 weight matrices (1024 f4 each).
    const f4* w1v = (const f4*)W1;
    const f4* w2v = (const f4*)W2;
    f4* s1 = (f4*)&sW1[0][0];
    f4* s2 = (f4*)&sW2[0][0];
#pragma unroll
    for (int i = 0; i < 4; ++i) {
        s1[tid + i * 256] = w1v[tid + i * 256];
        s2[tid + i * 256] = w2v[tid + i * 256];
    }
    const int row0 = blockIdx.x * 4;
    if (tid < 64) ((f4*)&sE[0][0])[tid] = ((const f4*)(emb_node + row0 * 64))[tid];
    __syncthreads();

    const int s = tid >> 6;    // row within block (0..3)
    const int f = tid & 63;    // output feature
    float a1 = b1[f];
    float a2 = b2[f];
#pragma unroll
    for (int k = 0; k < 64; ++k) {
        const float e = sE[s][k];              // broadcast read
        a1 = fmaf(e, sW1[k][f], a1);           // 2-way bank alias: free
        a2 = fmaf(e, sW2[k][f], a2);
    }
    const int row = row0 + s;
    g_node_x[row * 64 + f]  = a1;              // pre-relu (used inside einsum)
    g_relu_sx[row * 64 + f] = fmaxf(a2, 0.f);
}

// ---------------------------------------------------------------------------
// Kernel 2: per (b,n) block — edge GEMM [256,32]@[32,64] with register tiling
// (8 m x 4 f x 4 k per thread), fused relu-store of edge_out and the
// A*edge*node_x aggregation, LDS reduce over m-groups, write node_out.
// 2048 blocks x 512 threads. LDS = 54.5 KB -> 2 blocks/CU.
// ---------------------------------------------------------------------------
__global__ __launch_bounds__(512, 4) void edge_agg(
    const float* __restrict__ A,         // [B,N,N]
    const float* __restrict__ emb_edge,  // [B,N,N,32]
    const float* __restrict__ W_edge,    // [32,64]
    const float* __restrict__ b_edge,    // [64]
    float* __restrict__ node_out,        // [B,N,64]
    float* __restrict__ edge_out)        // [B,N,N,64]
{
    // Row pad 32 -> 36 floats: in-wave m-addresses (stride 144 B) start at
    // banks {0,4,8,12} -> conflict-free ds_read_b128; keeps 16 B alignment.
    __shared__ float sE[256][36];   // 36864 B
    __shared__ float sW[32][64];    //  8192 B
    __shared__ float sA[256];       //  1024 B
    __shared__ float sRed[32][64];  //  8192 B

    const int tid = threadIdx.x;
    const int bn  = blockIdx.x;       // 0..2047 == b*256+n
    const int b   = bn >> 8;

    // ---- stage emb_edge rows for this (b,n): 8192 floats = 2048 f4 ----
    const float* embBase = emb_edge + (size_t)bn * (NN * INE);
#pragma unroll
    for (int it = 0; it < 4; ++it) {
        const int i  = tid + it * 512;
        const f4   v = __builtin_nontemporal_load(((const f4*)embBase) + i);
        const int m  = i >> 3;        // 8 f4 per 32-float row
        const int k4 = i & 7;
        *(f4*)&sE[m][k4 * 4] = v;
    }
    // ---- stage W_edge (512 f4) and A row (64 f4) ----
    ((f4*)&sW[0][0])[tid] = ((const f4*)W_edge)[tid];
    if (tid < 64) ((f4*)sA)[tid] = ((const f4*)(A + bn * NN))[tid];
    __syncthreads();

    const int fg = tid & 15;          // 16 f-groups of 4
    const int mg = tid >> 4;          // 32 m-groups (rows mg, mg+32, ..., mg+224)
    const int f0 = fg * 4;

    const f4 bias = *(const f4*)(b_edge + f0);
    float acc[8][4];
#pragma unroll
    for (int i = 0; i < 8; ++i) {
        acc[i][0] = bias.x; acc[i][1] = bias.y; acc[i][2] = bias.z; acc[i][3] = bias.w;
    }

    // ---- register-tiled GEMM: per k-chunk, 12 ds_read_b128 feed 128 FMAs ----
#pragma unroll
    for (int k4 = 0; k4 < 8; ++k4) {
        f4 ev[8];
#pragma unroll
        for (int i = 0; i < 8; ++i)
            ev[i] = *(const f4*)&sE[mg + i * 32][k4 * 4];
#pragma unroll
        for (int kk = 0; kk < 4; ++kk) {
            const f4 w = *(const f4*)&sW[k4 * 4 + kk][f0];
#pragma unroll
            for (int i = 0; i < 8; ++i) {
                const float e = (kk == 0) ? ev[i].x
                              : (kk == 1) ? ev[i].y
                              : (kk == 2) ? ev[i].z
                                          : ev[i].w;
                acc[i][0] = fmaf(e, w.x, acc[i][0]);
                acc[i][1] = fmaf(e, w.y, acc[i][1]);
                acc[i][2] = fmaf(e, w.z, acc[i][2]);
                acc[i][3] = fmaf(e, w.w, acc[i][3]);
            }
        }
    }

    // ---- epilogue: relu-store edge_out, accumulate agg against node_x ----
    const float* nx = g_node_x + b * (NN * OUTF);
    const size_t outBase = (size_t)bn * (NN * OUTE);
    float agg0 = 0.f, agg1 = 0.f, agg2 = 0.f, agg3 = 0.f;
#pragma unroll
    for (int i = 0; i < 8; ++i) {
        const int m = mg + i * 32;
        const float a = sA[m];                          // broadcast
        const f4 nxv = *(const f4*)&nx[m * 64 + f0];    // L2-hot
        f4 st;
        st.x = fmaxf(acc[i][0], 0.f);
        st.y = fmaxf(acc[i][1], 0.f);
        st.z = fmaxf(acc[i][2], 0.f);
        st.w = fmaxf(acc[i][3], 0.f);
        __builtin_nontemporal_store(st, (f4*)&edge_out[outBase + (size_t)m * 64 + f0]);
        // agg uses PRE-relu edge_x and PRE-relu node_x
        agg0 = fmaf(a * acc[i][0], nxv.x, agg0);
        agg1 = fmaf(a * acc[i][1], nxv.y, agg1);
        agg2 = fmaf(a * acc[i][2], nxv.z, agg2);
        agg3 = fmaf(a * acc[i][3], nxv.w, agg3);
    }
    f4 aggv; aggv.x = agg0; aggv.y = agg1; aggv.z = agg2; aggv.w = agg3;
    *(f4*)&sRed[mg][f0] = aggv;
    __syncthreads();

    // ---- reduce 32 m-group partials, add relu(node_sx), store node_out ----
    if (tid < 64) {
        float s = 0.f;
#pragma unroll
        for (int g = 0; g < 32; ++g) s += sRed[g][tid];
        node_out[bn * 64 + tid] = fmaxf(s, 0.f) + g_relu_sx[bn * 64 + tid];
    }
}

// ---------------------------------------------------------------------------
extern "C" void kernel_launch(void* const* d_in, const int* in_sizes, int n_in,
                              void* d_out, int out_size, void* d_ws, size_t ws_size,
                              hipStream_t stream) {
    const float* A        = (const float*)d_in[0];
    const float* emb_node = (const float*)d_in[1];
    const float* emb_edge = (const float*)d_in[2];
    const float* W_node   = (const float*)d_in[3];
    const float* b_node   = (const float*)d_in[4];
    const float* W_nodes  = (const float*)d_in[5];
    const float* b_nodes  = (const float*)d_in[6];
    const float* W_edge   = (const float*)d_in[7];
    const float* b_edge   = (const float*)d_in[8];

    float* node_out = (float*)d_out;                 // [8,256,64]
    float* edge_out = node_out + BB * NN * OUTF;     // [8,256,256,64]

    node_proj<<<(BB * NN) / 4, 256, 0, stream>>>(emb_node, W_node, b_node, W_nodes, b_nodes);
    edge_agg<<<BB * NN, 512, 0, stream>>>(A, emb_edge, W_edge, b_edge, node_out, edge_out);
}